// Round 2
// baseline (26745.044 us; speedup 1.0000x reference)
//
#include <hip/hip_runtime.h>

#define TSTEPS 512
#define BATCH  64
#define FEAT   512
#define HID    1024
#define NWG    256
#define NTHR   256
#define WPL    (BATCH * HID / 4)   // 16384 ull words per h snapshot (128 KB)
#define STGULL 40960               // per-XCD stage stride in ull: h0(16384)+h1(16384)+x(8192)
#define AGENT  __HIP_MEMORY_SCOPE_AGENT

typedef unsigned long long ull;
typedef _Float16 half8_t  __attribute__((ext_vector_type(8)));
typedef _Float16 half4_t  __attribute__((ext_vector_type(4)));
typedef float    float4_t __attribute__((ext_vector_type(4)));

__device__ __forceinline__ float sigf(float x)      { return 1.0f / (1.0f + __expf(-x)); }
__device__ __forceinline__ float tanh_fast(float x) { return 2.0f / (1.0f + __expf(-2.0f * x)) - 1.0f; }

// ---- round-0-proven grid barrier: release arrive, relaxed poll, one acquire
// fence per wave on exit. bar[0]=gen, bar[32]=root, bar[64+32*x]=line[x]. ----
__device__ __forceinline__ void grid_barrier(unsigned* bar, int line_id, unsigned step) {
    __syncthreads();                       // drains all waves' vmem to L2
    if (threadIdx.x == 0) {
        unsigned* gen  = bar;
        unsigned* root = bar + 32;
        unsigned* line = bar + 64 + 32 * line_id;
        unsigned old = __hip_atomic_fetch_add(line, 1u, __ATOMIC_RELEASE, AGENT);
        if (old == 32u * step - 1u) {
            unsigned r = __hip_atomic_fetch_add(root, 1u, __ATOMIC_RELEASE, AGENT);
            if (r == 8u * step - 1u)
                __hip_atomic_store(gen, step, __ATOMIC_RELEASE, AGENT);
        }
        while (__hip_atomic_load(gen, __ATOMIC_RELAXED, AGENT) < step)
            __builtin_amdgcn_s_sleep(1);
    }
    __syncthreads();
    __builtin_amdgcn_fence(__ATOMIC_ACQUIRE, "agent");   // one inv per wave
}

// Per-XCD barrier. Release arrive (wbl2 -> stage data safe even if XCD
// grouping is ever wrong), relaxed poll, NO acquire on exit: the grid
// barrier's fence this step already inv'd L1/L2 before any stage write,
// so same-L2 plain reads after this point are fresh.
__device__ __forceinline__ void xbar_sync(unsigned* xb, int tid, unsigned target) {
    __syncthreads();                       // drains crew stores into L2
    if (tid == 0) {
        __hip_atomic_fetch_add(xb, 1u, __ATOMIC_RELEASE, AGENT);
        while (__hip_atomic_load(xb, __ATOMIC_RELAXED, AGENT) < target)
            __builtin_amdgcn_s_sleep(1);
    }
    __syncthreads();
    asm volatile("" ::: "memory");
    __builtin_amdgcn_sched_barrier(0);
}

// crew copy: MALL exchange buffers -> this XCD's stage region (plain loads,
// plain stores). Also transposes+converts x(t2) fp32 -> fp16 [b][f].
__device__ __forceinline__ void crew_copy(ull* stg, const ull* h0src, const ull* h1src,
                                          const float* x, int t2, int do_x,
                                          int slot, int tid, int crewN) {
    if (crewN == 32) {                       // exact path: 8192 threads
        int idx = slot * NTHR + tid;         // [0, 8192)
        ull a = h0src[idx];
        ull b = h0src[idx + 8192];
        ull c = h1src[idx];
        ull d = h1src[idx + 8192];
        stg[idx]         = a;  stg[idx + 8192]         = b;
        stg[16384 + idx] = c;  stg[16384 + idx + 8192] = d;
        if (do_x) {
            int bb = idx >> 7, f4 = idx & 127;
            float4_t v = *(const float4_t*)(x + ((size_t)bb * TSTEPS + t2) * FEAT + f4 * 4);
            half4_t h;
            h.x = (_Float16)v.x; h.y = (_Float16)v.y; h.z = (_Float16)v.z; h.w = (_Float16)v.w;
            ((half4_t*)(stg + 32768))[idx] = h;
        }
    } else {                                 // robust fallback, any crew size
        for (int w = slot * NTHR + tid; w < 16384; w += crewN * NTHR) {
            stg[w]         = h0src[w];
            stg[16384 + w] = h1src[w];
        }
        if (do_x)
            for (int idx = slot * NTHR + tid; idx < 8192; idx += crewN * NTHR) {
                int bb = idx >> 7, f4 = idx & 127;
                float4_t v = *(const float4_t*)(x + ((size_t)bb * TSTEPS + t2) * FEAT + f4 * 4);
                half4_t h;
                h.x = (_Float16)v.x; h.y = (_Float16)v.y; h.z = (_Float16)v.z; h.w = (_Float16)v.w;
                ((half4_t*)(stg + 32768))[idx] = h;
            }
    }
}

// Persistent 2-layer LSTM with per-XCD L2 staging of the h/x broadcast.
// 256 WGs (1/CU), each owns 4 hidden units/layer; weights fp16 in LDS.
// Per step: read stage (L2-hit) -> L1(t) -> L0(t+1) -> plain h stores to
// MALL-side exchange -> grid barrier (unchanged from round 0) -> crew copies
// {h0(t+1), h1(t), x(t+2)} into XCD stage -> xbar.
__global__ __launch_bounds__(NTHR, 1) void lstm_persistent4(
    const float* __restrict__ Wih0, const float* __restrict__ Whh0,
    const float* __restrict__ bih0, const float* __restrict__ bhh0,
    const float* __restrict__ Wih1, const float* __restrict__ Whh1,
    const float* __restrict__ bih1, const float* __restrict__ bhh1,
    const float* __restrict__ xf,   // x [64][512][512] fp32 (no transpose pass)
    ull* __restrict__ hx0,          // [2][WPL] h0 exchange
    ull* __restrict__ hx1,          // [2][WPL] h1 exchange
    ull* __restrict__ stage,        // [16][STGULL] per-XCD staging
    unsigned* __restrict__ bar,
    float* __restrict__ out)        // out[64][512][1024] | hT[2][64][1024] | cT[2][64][1024]
{
    extern __shared__ __align__(16) char smem[];
    _Float16* w0x = (_Float16*)smem;        // [ 64][16][8]  K=512  (W_ih_0 slice)
    _Float16* w0h = w0x + 16 * FEAT;        // [128][16][8]  K=1024 (W_hh_0 slice)
    _Float16* w1  = w0h + 16 * HID;         // [256][16][8]  K=2048 (W_ih_1 ++ W_hh_1)
    int* comm = (int*)(w1 + 16 * 2048);     // [xcd, slot, crewN]

    const int wg  = blockIdx.x;
    const int u0  = ((wg & 7) * 32 + (wg >> 3)) * 4;
    const int tid = threadIdx.x;

    unsigned* crewcnt = bar + 512;    // [16] stride 32
    unsigned* xbars   = bar + 1024;   // [16] stride 32

    if (tid == 0) {
        unsigned xcc = __builtin_amdgcn_s_getreg(63508) & 15u;  // hwreg(HW_REG_XCC_ID=20,0,32)
        unsigned slot = __hip_atomic_fetch_add(crewcnt + 32 * xcc, 1u, __ATOMIC_RELAXED, AGENT);
        comm[0] = (int)xcc;
        comm[1] = (int)slot;
    }

    // ---- one-time: fp32 weight slices -> fp16 LDS A-fragments ----
    for (int idx = tid; idx < 16 * FEAT; idx += NTHR) {
        int m = idx >> 9, k = idx & (FEAT - 1);
        int grow = (m & 3) * HID + u0 + (m >> 2);
        w0x[(((k >> 3) * 16) + m) * 8 + (k & 7)] = (_Float16)Wih0[grow * FEAT + k];
    }
    for (int idx = tid; idx < 16 * HID; idx += NTHR) {
        int m = idx >> 10, k = idx & (HID - 1);
        int grow = (m & 3) * HID + u0 + (m >> 2);
        w0h[(((k >> 3) * 16) + m) * 8 + (k & 7)] = (_Float16)Whh0[grow * HID + k];
    }
    for (int idx = tid; idx < 16 * 2048; idx += NTHR) {
        int m = idx >> 11, k = idx & 2047;
        int grow = (m & 3) * HID + u0 + (m >> 2);
        float v = (k < HID) ? Wih1[grow * HID + k] : Whh1[grow * HID + (k - HID)];
        w1[(((k >> 3) * 16) + m) * 8 + (k & 7)] = (_Float16)v;
    }

    const int lane  = tid & 63;
    const int wv    = tid >> 6;      // wave -> 16-batch tile
    const int q     = lane >> 4;     // quad: local unit (C) / k-block (A,B)
    const int n     = lane & 15;     // col: batch (C/B) / row m (A)
    const int batch = wv * 16 + n;
    const int unit  = u0 + q;

    float b0r[4], b1r[4];
#pragma unroll
    for (int r = 0; r < 4; ++r) {
        int grow = r * HID + unit;
        b0r[r] = bih0[grow] + bhh0[grow];
        b1r[r] = bih1[grow] + bhh1[grow];
    }

    __syncthreads();

    const int xcd  = comm[0];
    const int slot = comm[1];
    unsigned* xbar = xbars + 32 * xcd;
    ull* stg       = stage + (size_t)xcd * STGULL;
    const _Float16* sh   = (const _Float16*)stg;
    const _Float16* myh0 = sh + batch * HID + q * 8;                   // stage h0
    const _Float16* myh1 = sh + BATCH * HID + batch * HID + q * 8;     // stage h1
    const _Float16* myx  = sh + 2 * BATCH * HID + batch * FEAT + q * 8;// stage x

    _Float16* hx0h = (_Float16*)hx0;
    _Float16* hx1h = (_Float16*)hx1;

    const half8_t* a0x = (const half8_t*)w0x;
    const half8_t* a0h = (const half8_t*)w0h;
    const half8_t* a1  = (const half8_t*)w1;
    const float4_t fzero = {0.f, 0.f, 0.f, 0.f};

    float c0 = 0.f, c1 = 0.f, h0v = 0.f, h1v = 0.f;
    float4_t acc[4];

    // ---- prologue: L0(0): gates = x_0 @ Wih0^T + b  (h0_prev = 0), x fp32 ----
    {
        const float* xb = xf + (size_t)batch * (TSTEPS * FEAT) + q * 8;  // x[b][0][q*8]
        acc[0] = fzero; acc[1] = fzero; acc[2] = fzero; acc[3] = fzero;
#pragma unroll
        for (int s = 0; s < 16; ++s) {
            float4_t v0 = *(const float4_t*)(xb + s * 32);
            float4_t v1 = *(const float4_t*)(xb + s * 32 + 4);
            half8_t xfr;
            xfr[0] = (_Float16)v0.x; xfr[1] = (_Float16)v0.y;
            xfr[2] = (_Float16)v0.z; xfr[3] = (_Float16)v0.w;
            xfr[4] = (_Float16)v1.x; xfr[5] = (_Float16)v1.y;
            xfr[6] = (_Float16)v1.z; xfr[7] = (_Float16)v1.w;
            acc[s & 3] = __builtin_amdgcn_mfma_f32_16x16x32_f16(
                a0x[(s * 4 + q) * 16 + n], xfr, acc[s & 3], 0, 0, 0);
        }
        float4_t g = (acc[0] + acc[1]) + (acc[2] + acc[3]);
        float I = sigf(g.x + b0r[0]);
        float G = tanh_fast(g.z + b0r[2]);
        float O = sigf(g.w + b0r[3]);
        c0  = I * G;                   // f * c_prev = 0
        h0v = O * tanh_fast(c0);
        hx0h[batch * HID + unit] = (_Float16)h0v;      // h0(0) -> hx0 buffer 0
    }
    grid_barrier(bar, wg & 7, 1u);
    if (tid == 0)
        comm[2] = (int)__hip_atomic_load(crewcnt + 32 * xcd, __ATOMIC_RELAXED, AGENT);
    __syncthreads();
    const int crewN = comm[2];
    // stage <- {h0(0), h1(-1)=0 (hx1 buffer 1, zeroed), x(1)}
    crew_copy(stg, hx0, hx1 + WPL, xf, 1, 1, slot, tid, crewN);
    xbar_sync(xbar, tid, (unsigned)crewN);

    for (int t = 0; t < TSTEPS; ++t) {
        // ---- stage reads (same-XCD L2 hits) ----
        half8_t p0r[32];
#pragma unroll
        for (int s = 0; s < 32; ++s) p0r[s] = *(const half8_t*)(myh0 + s * 32);

        // ---- layer 1 at t: gates = h0(t)@Wih1^T + h1(t-1)@Whh1^T + b ----
        acc[0] = fzero; acc[1] = fzero; acc[2] = fzero; acc[3] = fzero;
#pragma unroll 8
        for (int s = 0; s < 32; ++s)
            acc[s & 3] = __builtin_amdgcn_mfma_f32_16x16x32_f16(
                a1[(s * 4 + q) * 16 + n], p0r[s], acc[s & 3], 0, 0, 0);
#pragma unroll 8
        for (int s = 0; s < 32; ++s)
            acc[s & 3] = __builtin_amdgcn_mfma_f32_16x16x32_f16(
                a1[(128 + s * 4 + q) * 16 + n], *(const half8_t*)(myh1 + s * 32), acc[s & 3], 0, 0, 0);
        {
            float4_t g = (acc[0] + acc[1]) + (acc[2] + acc[3]);
            float I = sigf(g.x + b1r[0]);
            float F = sigf(g.y + b1r[1]);
            float G = tanh_fast(g.z + b1r[2]);
            float O = sigf(g.w + b1r[3]);
            c1  = F * c1 + I * G;
            h1v = O * tanh_fast(c1);
        }
        out[((size_t)batch * TSTEPS + t) * HID + unit] = h1v;

        if (t + 1 < TSTEPS) {
            hx1h[(t & 1) * (BATCH * HID) + batch * HID + unit] = (_Float16)h1v;

            // ---- layer 0 at t+1: x(t+1)@Wih0^T + h0(t)@Whh0^T + b ----
            acc[0] = fzero; acc[1] = fzero; acc[2] = fzero; acc[3] = fzero;
#pragma unroll 8
            for (int s = 0; s < 16; ++s)
                acc[s & 3] = __builtin_amdgcn_mfma_f32_16x16x32_f16(
                    a0x[(s * 4 + q) * 16 + n], *(const half8_t*)(myx + s * 32), acc[s & 3], 0, 0, 0);
#pragma unroll 8
            for (int s = 0; s < 32; ++s)
                acc[s & 3] = __builtin_amdgcn_mfma_f32_16x16x32_f16(
                    a0h[(s * 4 + q) * 16 + n], p0r[s], acc[s & 3], 0, 0, 0);
            {
                float4_t g = (acc[0] + acc[1]) + (acc[2] + acc[3]);
                float I = sigf(g.x + b0r[0]);
                float F = sigf(g.y + b0r[1]);
                float G = tanh_fast(g.z + b0r[2]);
                float O = sigf(g.w + b0r[3]);
                c0  = F * c0 + I * G;
                h0v = O * tanh_fast(c0);
            }
            hx0h[((t + 1) & 1) * (BATCH * HID) + batch * HID + unit] = (_Float16)h0v;

            grid_barrier(bar, wg & 7, (unsigned)(t + 2));
            // stage <- {h0(t+1), h1(t), x(t+2)}
            crew_copy(stg,
                      hx0 + (size_t)((t + 1) & 1) * WPL,
                      hx1 + (size_t)(t & 1) * WPL,
                      xf, t + 2, (t + 2 < TSTEPS) ? 1 : 0,
                      slot, tid, crewN);
            xbar_sync(xbar, tid, (unsigned)crewN * (unsigned)(t + 2));
        }
    }

    float* hT = out + (size_t)BATCH * TSTEPS * HID;
    float* cT = hT + 2 * BATCH * HID;
    hT[batch * HID + unit]               = h0v;
    hT[BATCH * HID + batch * HID + unit] = h1v;
    cT[batch * HID + unit]               = c0;
    cT[BATCH * HID + batch * HID + unit] = c1;
}

extern "C" void kernel_launch(void* const* d_in, const int* in_sizes, int n_in,
                              void* d_out, int out_size, void* d_ws, size_t ws_size,
                              hipStream_t stream) {
    (void)in_sizes; (void)n_in; (void)out_size; (void)ws_size;
    const float* x    = (const float*)d_in[0];
    const float* Wih0 = (const float*)d_in[1];
    const float* Whh0 = (const float*)d_in[2];
    const float* bih0 = (const float*)d_in[3];
    const float* bhh0 = (const float*)d_in[4];
    const float* Wih1 = (const float*)d_in[5];
    const float* Whh1 = (const float*)d_in[6];
    const float* bih1 = (const float*)d_in[7];
    const float* bhh1 = (const float*)d_in[8];

    char* ws = (char*)d_ws;
    unsigned* bar = (unsigned*)ws;                         // 8 KB barrier/meta area
    ull* hx0      = (ull*)(ws + (64 << 10));               // 256 KB ([2][WPL])
    ull* hx1      = (ull*)(ws + (64 << 10) + (256 << 10)); // 256 KB
    ull* stage    = (ull*)(ws + (1 << 20));                // 5 MB ([16][STGULL]); total 6 MB << 33 MB proven
    hipMemsetAsync(d_ws, 0, 1 << 20, stream);              // zero barrier + hx bufs

    const int shmem = 16 * (FEAT + HID + 2048) * (int)sizeof(_Float16) + 256;  // 114944 B
    hipFuncSetAttribute((const void*)lstm_persistent4,
                        hipFuncAttributeMaxDynamicSharedMemorySize, shmem);
    lstm_persistent4<<<NWG, NTHR, shmem, stream>>>(
        Wih0, Whh0, bih0, bhh0, Wih1, Whh1, bih1, bhh1,
        x, hx0, hx1, stage, bar, (float*)d_out);
}

// Round 5
// 20460.963 us; speedup vs baseline: 1.3071x; 1.3071x over previous
//
#include <hip/hip_runtime.h>

#define TSTEPS 512
#define BATCH  64
#define FEAT   512
#define HID    1024
#define NWG    256
#define NTHR   256
#define AGENT  __HIP_MEMORY_SCOPE_AGENT

typedef _Float16 half8_t  __attribute__((ext_vector_type(8)));
typedef _Float16 half4_t  __attribute__((ext_vector_type(4)));
typedef float    float4_t __attribute__((ext_vector_type(4)));

__device__ __forceinline__ float sigf(float x)      { return 1.0f / (1.0f + __expf(-x)); }
__device__ __forceinline__ float tanh_fast(float x) { return 2.0f / (1.0f + __expf(-2.0f * x)) - 1.0f; }

// x[b][t][f] fp32 -> xT[t][b][f] fp16   (round-0 proven)
__global__ void xpose_kernel(const float* __restrict__ x, _Float16* __restrict__ xT) {
    int idx = blockIdx.x * NTHR + threadIdx.x;   // over B*T*F/4
    int f4 = idx & 127;                          // F/4 = 128
    int bt = idx >> 7;                           // b*T + t
    int t = bt & (TSTEPS - 1);
    int b = bt >> 9;
    float4_t v = ((const float4_t*)x)[idx];
    half4_t h;
    h.x = (_Float16)v.x; h.y = (_Float16)v.y; h.z = (_Float16)v.z; h.w = (_Float16)v.w;
    *(half4_t*)(xT + (size_t)(t * BATCH + b) * FEAT + f4 * 4) = h;
}

// Round-0 grid barrier with the acquire fence DELEGATED to one WG per XCD.
// Arrive chain (release fetch_adds -> wbl2 flush of this XCD's dirty h lines)
// and relaxed gen poll are byte-for-byte the round-0-proven mechanism. After
// gen flips, ALL h stores grid-wide are at MALL. Then slot-0 (one WG per XCD,
// census proven in round 2) executes the ONLY buffer_inv of this XCD for the
// step and release-publishes epoch[xcd] (release = vmcnt-wait orders the inv
// completion before the flag). The other 31 WGs poll epoch and then read h
// with PLAIN loads: first toucher misses to MALL (fresh), fills L2, 31
// neighbors hit L2 -> the 32x intra-XCD broadcast is served locally.
// bar[0]=gen, bar[32]=root, bar[64+32*x]=line[x], bar[512+32*x]=crewcnt[x],
// bar[1024+32*x]=epoch[x]  (all zero-init).
__device__ __forceinline__ void grid_barrier_x(unsigned* bar, int line_id, unsigned step,
                                               unsigned my_slot, unsigned my_xcd) {
    __syncthreads();                       // drains all waves' vmem to L2
    if (threadIdx.x == 0) {
        unsigned* gen   = bar;
        unsigned* root  = bar + 32;
        unsigned* line  = bar + 64 + 32 * line_id;
        unsigned* epoch = bar + 1024 + 32 * my_xcd;
        unsigned old = __hip_atomic_fetch_add(line, 1u, __ATOMIC_RELEASE, AGENT);
        if (old == 32u * step - 1u) {
            unsigned r = __hip_atomic_fetch_add(root, 1u, __ATOMIC_RELEASE, AGENT);
            if (r == 8u * step - 1u)
                __hip_atomic_store(gen, step, __ATOMIC_RELEASE, AGENT);
        }
        while (__hip_atomic_load(gen, __ATOMIC_RELAXED, AGENT) < step)
            __builtin_amdgcn_s_sleep(1);
        if (my_slot == 0) {
            __builtin_amdgcn_fence(__ATOMIC_ACQUIRE, "agent");  // ONE inv per XCD
            __hip_atomic_store(epoch, step, __ATOMIC_RELEASE, AGENT);
        } else {
            while (__hip_atomic_load(epoch, __ATOMIC_RELAXED, AGENT) < step)
                __builtin_amdgcn_s_sleep(1);
        }
    }
    __syncthreads();
    asm volatile("" ::: "memory");
}

// Persistent 2-layer LSTM — round-0 structure and compute path, unchanged.
// 256 WGs (1/CU, LDS-forced), each owns 4 hidden units per layer; weights
// fp16 in LDS in [kb][m][8] A-fragment layout. Plain loads everywhere.
__global__ __launch_bounds__(NTHR, 1) void lstm_persistent7(
    const float* __restrict__ Wih0, const float* __restrict__ Whh0,
    const float* __restrict__ bih0, const float* __restrict__ bhh0,
    const float* __restrict__ Wih1, const float* __restrict__ Whh1,
    const float* __restrict__ bih1, const float* __restrict__ bhh1,
    const _Float16* __restrict__ xT,
    _Float16* __restrict__ h0buf,   // [2][64][1024] fp16
    _Float16* __restrict__ h1buf,   // [2][64][1024] fp16
    unsigned* __restrict__ bar,
    float* __restrict__ out)        // out[64][512][1024] | hT[2][64][1024] | cT[2][64][1024]
{
    extern __shared__ __align__(16) char smem[];
    _Float16* w0x = (_Float16*)smem;        // [ 64][16][8]  K=512  (W_ih_0 slice)
    _Float16* w0h = w0x + 16 * FEAT;        // [128][16][8]  K=1024 (W_hh_0 slice)
    _Float16* w1  = w0h + 16 * HID;         // [256][16][8]  K=2048 (W_ih_1 ++ W_hh_1)

    const int wg  = blockIdx.x;
    const int u0  = ((wg & 7) * 32 + (wg >> 3)) * 4;  // XCD-contiguous unit blocks
    const int tid = threadIdx.x;

    // one-time XCD census (round-2 proven): exactly one slot-0 WG per XCD.
    unsigned my_xcd = 0, my_slot = 1;
    if (tid == 0) {
        unsigned* crewcnt = bar + 512;   // [16] stride 32, zero-init
        my_xcd  = __builtin_amdgcn_s_getreg(63508) & 15u;  // hwreg(HW_REG_XCC_ID=20,0,32)
        my_slot = __hip_atomic_fetch_add(crewcnt + 32 * my_xcd, 1u, __ATOMIC_RELAXED, AGENT);
    }

    // ---- one-time: convert fp32 weight slices -> fp16 LDS fragments ----
    for (int idx = tid; idx < 16 * FEAT; idx += NTHR) {
        int m = idx >> 9, k = idx & (FEAT - 1);
        int grow = (m & 3) * HID + u0 + (m >> 2);
        w0x[(((k >> 3) * 16) + m) * 8 + (k & 7)] = (_Float16)Wih0[grow * FEAT + k];
    }
    for (int idx = tid; idx < 16 * HID; idx += NTHR) {
        int m = idx >> 10, k = idx & (HID - 1);
        int grow = (m & 3) * HID + u0 + (m >> 2);
        w0h[(((k >> 3) * 16) + m) * 8 + (k & 7)] = (_Float16)Whh0[grow * HID + k];
    }
    for (int idx = tid; idx < 16 * 2048; idx += NTHR) {
        int m = idx >> 11, k = idx & 2047;
        int grow = (m & 3) * HID + u0 + (m >> 2);
        float v = (k < HID) ? Wih1[grow * HID + k] : Whh1[grow * HID + (k - HID)];
        w1[(((k >> 3) * 16) + m) * 8 + (k & 7)] = (_Float16)v;
    }

    const int lane  = tid & 63;
    const int wv    = tid >> 6;      // wave -> 16-batch tile
    const int q     = lane >> 4;     // quad: local unit (for C) / k-block (for A,B)
    const int n     = lane & 15;     // col: batch (for C/B) / row m (for A)
    const int batch = wv * 16 + n;
    const int unit  = u0 + q;

    float b0r[4], b1r[4];
#pragma unroll
    for (int r = 0; r < 4; ++r) {
        int grow = r * HID + unit;
        b0r[r] = bih0[grow] + bhh0[grow];
        b1r[r] = bih1[grow] + bhh1[grow];
    }

    __syncthreads();

    const half8_t* a0x = (const half8_t*)w0x;
    const half8_t* a0h = (const half8_t*)w0h;
    const half8_t* a1  = (const half8_t*)w1;
    const float4_t fzero = {0.f, 0.f, 0.f, 0.f};

    float c0 = 0.f, c1 = 0.f, h0v = 0.f, h1v = 0.f;
    float4_t acc[4];
    half8_t  xreg[16];

    // ---- prologue: L0(0): gates = x_0 @ Wih0^T + b   (h0_prev = 0) ----
    {
        const _Float16* xb = xT + (size_t)batch * FEAT + q * 8;
        acc[0] = fzero; acc[1] = fzero; acc[2] = fzero; acc[3] = fzero;
#pragma unroll
        for (int s = 0; s < 16; ++s)
            acc[s & 3] = __builtin_amdgcn_mfma_f32_16x16x32_f16(
                a0x[(s * 4 + q) * 16 + n], *(const half8_t*)(xb + s * 32), acc[s & 3], 0, 0, 0);
        float4_t g = (acc[0] + acc[1]) + (acc[2] + acc[3]);
        float I = sigf(g.x + b0r[0]);
        float G = tanh_fast(g.z + b0r[2]);
        float O = sigf(g.w + b0r[3]);
        c0  = I * G;                   // f * c_prev = 0
        h0v = O * tanh_fast(c0);
        h0buf[batch * HID + unit] = (_Float16)h0v;     // buffer 0 = h0(0)
    }
    {   // prefetch x(1)
        const _Float16* xb = xT + ((size_t)BATCH + batch) * FEAT + q * 8;
#pragma unroll
        for (int s = 0; s < 16; ++s) xreg[s] = *(const half8_t*)(xb + s * 32);
    }
    grid_barrier_x(bar, wg & 7, 1u, my_slot, my_xcd);

    for (int t = 0; t < TSTEPS; ++t) {
        // ---- p0 = h0(t) fragments: feed L1(t) now, L0(t+1) later ----
        const _Float16* h0cur = h0buf + (t & 1) * (BATCH * HID) + batch * HID + q * 8;
        half8_t p0r[32];
#pragma unroll
        for (int s = 0; s < 32; ++s) p0r[s] = *(const half8_t*)(h0cur + s * 32);

        // ---------- layer 1: gates = h0(t)@Wih1^T + h1(t-1)@Whh1^T + b ----------
        acc[0] = fzero; acc[1] = fzero; acc[2] = fzero; acc[3] = fzero;
#pragma unroll 8
        for (int s = 0; s < 32; ++s)
            acc[s & 3] = __builtin_amdgcn_mfma_f32_16x16x32_f16(
                a1[(s * 4 + q) * 16 + n], p0r[s], acc[s & 3], 0, 0, 0);
        {
            const _Float16* p1 = h1buf + ((t & 1) ^ 1) * (BATCH * HID) + batch * HID + q * 8;
#pragma unroll 8
            for (int s = 0; s < 32; ++s)
                acc[s & 3] = __builtin_amdgcn_mfma_f32_16x16x32_f16(
                    a1[(128 + s * 4 + q) * 16 + n], *(const half8_t*)(p1 + s * 32), acc[s & 3], 0, 0, 0);
        }
        {
            float4_t g = (acc[0] + acc[1]) + (acc[2] + acc[3]);
            float I = sigf(g.x + b1r[0]);
            float F = sigf(g.y + b1r[1]);
            float G = tanh_fast(g.z + b1r[2]);
            float O = sigf(g.w + b1r[3]);
            c1  = F * c1 + I * G;
            h1v = O * tanh_fast(c1);
        }
        h1buf[(t & 1) * (BATCH * HID) + batch * HID + unit] = (_Float16)h1v;
        out[((size_t)batch * TSTEPS + t) * HID + unit] = h1v;

        if (t + 1 < TSTEPS) {
            // ---- layer 0 at t+1 — consumes xreg (x(t+1)) and p0r (h0(t)) ----
            acc[0] = fzero; acc[1] = fzero; acc[2] = fzero; acc[3] = fzero;
#pragma unroll 8
            for (int s = 0; s < 16; ++s)
                acc[s & 3] = __builtin_amdgcn_mfma_f32_16x16x32_f16(
                    a0x[(s * 4 + q) * 16 + n], xreg[s], acc[s & 3], 0, 0, 0);
#pragma unroll 8
            for (int s = 0; s < 32; ++s)
                acc[s & 3] = __builtin_amdgcn_mfma_f32_16x16x32_f16(
                    a0h[(s * 4 + q) * 16 + n], p0r[s], acc[s & 3], 0, 0, 0);
            {
                float4_t g = (acc[0] + acc[1]) + (acc[2] + acc[3]);
                float I = sigf(g.x + b0r[0]);
                float F = sigf(g.y + b0r[1]);
                float G = tanh_fast(g.z + b0r[2]);
                float O = sigf(g.w + b0r[3]);
                c0  = F * c0 + I * G;
                h0v = O * tanh_fast(c0);
            }
            h0buf[((t + 1) & 1) * (BATCH * HID) + batch * HID + unit] = (_Float16)h0v;
            // refill xreg with x(t+2) AFTER consumption; overlaps barrier wait
            if (t + 2 < TSTEPS) {
                const _Float16* xb = xT + ((size_t)(t + 2) * BATCH + batch) * FEAT + q * 8;
#pragma unroll
                for (int s = 0; s < 16; ++s) xreg[s] = *(const half8_t*)(xb + s * 32);
            }
            grid_barrier_x(bar, wg & 7, (unsigned)(t + 2), my_slot, my_xcd);
        }
    }

    float* hT = out + (size_t)BATCH * TSTEPS * HID;
    float* cT = hT + 2 * BATCH * HID;
    hT[batch * HID + unit]               = h0v;
    hT[BATCH * HID + batch * HID + unit] = h1v;
    cT[batch * HID + unit]               = c0;
    cT[BATCH * HID + batch * HID + unit] = c1;
}

extern "C" void kernel_launch(void* const* d_in, const int* in_sizes, int n_in,
                              void* d_out, int out_size, void* d_ws, size_t ws_size,
                              hipStream_t stream) {
    (void)in_sizes; (void)n_in; (void)out_size; (void)ws_size;
    const float* x    = (const float*)d_in[0];
    const float* Wih0 = (const float*)d_in[1];
    const float* Whh0 = (const float*)d_in[2];
    const float* bih0 = (const float*)d_in[3];
    const float* bhh0 = (const float*)d_in[4];
    const float* Wih1 = (const float*)d_in[5];
    const float* Whh1 = (const float*)d_in[6];
    const float* bih1 = (const float*)d_in[7];
    const float* bhh1 = (const float*)d_in[8];

    char* ws = (char*)d_ws;
    unsigned* bar   = (unsigned*)ws;                 // 64 KB barrier area (gen/root/line/crewcnt/epoch)
    _Float16* h0buf = (_Float16*)(ws + (64 << 10));  // 256 KB [2][64][1024] (moved past epoch area)
    _Float16* h1buf = (_Float16*)(ws + (64 << 10) + (256 << 10));
    _Float16* xT    = (_Float16*)(ws + (1 << 20));   // 32 MB region (round-0 proven)

    hipMemsetAsync(d_ws, 0, 1 << 20, stream);        // zero barrier + h bufs

    xpose_kernel<<<(BATCH * TSTEPS * FEAT / 4) / NTHR, NTHR, 0, stream>>>(x, xT);

    const int shmem = 16 * (FEAT + HID + 2048) * (int)sizeof(_Float16);  // 114688 B
    hipFuncSetAttribute((const void*)lstm_persistent7,
                        hipFuncAttributeMaxDynamicSharedMemorySize, shmem);
    lstm_persistent7<<<NWG, NTHR, shmem, stream>>>(
        Wih0, Whh0, bih0, bhh0, Wih1, Whh1, bih1, bhh1,
        xT, h0buf, h1buf, bar, (float*)d_out);
}